// Round 1
// 651.943 us; speedup vs baseline: 1.0244x; 1.0244x over previous
//
#include <hip/hip_runtime.h>
#include <hip/hip_bf16.h>
#include <stdint.h>
#include <math.h>

// Problem constants (B=2,S=2048 -> T=4096 tokens), D=1024, U=4096, E=8, K=2
#define TTOK 4096
#define DDIM 1024
#define UDIM 4096
#define NEXP 8
#define KSPLIT 2            // split-K chunks for stage_down (K=4096 -> 2x2048)
#define KCH   (UDIM / KSPLIT)
#define NPAIR (TTOK * 2)
#define EPAD 72             // epilogue LDS bounce row stride (shorts)

using float4v = __attribute__((ext_vector_type(4))) float;
using short8  = __attribute__((ext_vector_type(8))) short;
using ushort8 = __attribute__((ext_vector_type(8))) unsigned short;

__device__ __forceinline__ unsigned short f2bf(float f) {
  union { float f; unsigned u; } v; v.f = f;
  unsigned r = v.u + 0x7FFFu + ((v.u >> 16) & 1u);  // RNE
  return (unsigned short)(r >> 16);
}
__device__ __forceinline__ float bf2f(unsigned short u) {
  union { unsigned u; float f; } v; v.u = ((unsigned)u) << 16;
  return v.f;
}
__device__ __forceinline__ void load_lds16(const void* g, void* l) {
  __builtin_amdgcn_global_load_lds(
      (const __attribute__((address_space(1))) unsigned int*)g,
      (__attribute__((address_space(3))) unsigned int*)l, 16, 0, 0);
}
// 8 fp32 -> 8 bf16 (RNE), packed
__device__ __forceinline__ short8 cvt8(const float4v a, const float4v b) {
  union { __hip_bfloat162 h[4]; short8 s; } u;
  u.h[0] = __float22bfloat162_rn(make_float2(a[0], a[1]));
  u.h[1] = __float22bfloat162_rn(make_float2(a[2], a[3]));
  u.h[2] = __float22bfloat162_rn(make_float2(b[0], b[1]));
  u.h[3] = __float22bfloat162_rn(make_float2(b[2], b[3]));
  return u.s;
}
// tanh-form gelu: v * sigmoid(2*0.797885*(v+0.044715 v^3)); NaN-safe at +-inf of exp
__device__ __forceinline__ float gelu_f(float v) {
  float u = v * (0.7978845608f + 0.0356774081f * v * v);
  float ex = __expf(2.0f * u);
  return v * (1.0f - 1.0f / (1.0f + ex));
}

// ---------------- router body: logits, top-2, softmax, lists; emits xb (bf16 x) ----------------
__device__ __forceinline__ void router_body(
    int t, int lane, const float* __restrict__ x, const float* __restrict__ wr,
    int* __restrict__ counts, int* __restrict__ list,
    float* __restrict__ wpair, int* __restrict__ epair,
    unsigned short* __restrict__ xb) {
  float acc[NEXP];
#pragma unroll
  for (int e = 0; e < NEXP; e++) acc[e] = 0.0f;
  const float* xr = x + (size_t)t * DDIM;
  unsigned short* xbr = xb + (size_t)t * DDIM;
  for (int d = lane; d < DDIM; d += 64) {
    float xv = xr[d];
    xbr[d] = f2bf(xv);
#pragma unroll
    for (int e = 0; e < NEXP; e++) acc[e] += xv * wr[e * DDIM + d];
  }
#pragma unroll
  for (int e = 0; e < NEXP; e++) {
#pragma unroll
    for (int off = 32; off > 0; off >>= 1) acc[e] += __shfl_xor(acc[e], off, 64);
  }
  if (lane == 0) {
    int e0 = 0; float l0 = acc[0];
    for (int e = 1; e < NEXP; e++) if (acc[e] > l0) { l0 = acc[e]; e0 = e; }
    int e1 = -1; float l1 = -3.4e38f;
    for (int e = 0; e < NEXP; e++) if (e != e0 && acc[e] > l1) { l1 = acc[e]; e1 = e; }
    float s1 = expf(l1 - l0);
    float inv = 1.0f / (1.0f + s1);
    int p0 = atomicAdd(&counts[e0], 1);
    list[e0 * TTOK + p0] = 2 * t;
    wpair[2 * t] = inv;  epair[2 * t] = e0;
    int p1 = atomicAdd(&counts[e1], 1);
    list[e1 * TTOK + p1] = 2 * t + 1;
    wpair[2 * t + 1] = s1 * inv;  epair[2 * t + 1] = e1;
  }
}

__global__ void router_kernel(const float* __restrict__ x,
                              const float* __restrict__ wr,
                              int* __restrict__ counts, int* __restrict__ list,
                              float* __restrict__ wpair, int* __restrict__ epair,
                              unsigned short* __restrict__ xb) {
  const int t = blockIdx.x * 4 + (threadIdx.x >> 6);
  router_body(t, threadIdx.x & 63, x, wr, counts, list, wpair, epair, xb);
}

// ---------------- prep: router (blocks 0..1023) + weight fp32->bf16 conversion (rest) ----------------
__global__ void prep_kernel(const float* __restrict__ x, const float* __restrict__ wr,
                            int* __restrict__ counts, int* __restrict__ list,
                            float* __restrict__ wpair, int* __restrict__ epair,
                            unsigned short* __restrict__ xb,
                            const float* __restrict__ wu, const float* __restrict__ wd,
                            unsigned short* __restrict__ wub, unsigned short* __restrict__ wdb) {
  const int bid = blockIdx.x;
  if (bid < TTOK / 4) {
    const int t = bid * 4 + (threadIdx.x >> 6);
    router_body(t, threadIdx.x & 63, x, wr, counts, list, wpair, epair, xb);
    return;
  }
  // BW-bound weight conversion: 2 tensors x 33.55M fp32 -> bf16 (RNE, identical to
  // the numerics the old per-tile cvt produced, just hoisted out of the GEMM loop)
  const size_t n8 = (size_t)NEXP * UDIM * DDIM / 8;   // 4,194,304 groups of 8
  const size_t cb = (size_t)(bid - TTOK / 4);
  const size_t stride = (size_t)(gridDim.x - TTOK / 4) * 256;
  for (size_t i = cb * 256 + threadIdx.x; i < 2 * n8; i += stride) {
    const float* s; unsigned short* d;
    if (i < n8) { s = wu + i * 8; d = wub + i * 8; }
    else        { s = wd + (i - n8) * 8; d = wdb + (i - n8) * 8; }
    float4v lo = *(const float4v*)s;
    float4v hi = *(const float4v*)(s + 4);
    short8 v = cvt8(lo, hi);
    *(short8*)d = v;
  }
}

// ======== bf16-weight stage A: h[pair,u] = gelu(x . Wup + bup). m97 K-loop:
// 4 global_load_lds (16KB), 8 ds_read_b128, 16 MFMA per K-step. ========
__global__ __launch_bounds__(256, 4) void stage_up_b16(
    const unsigned short* __restrict__ xb, const unsigned short* __restrict__ wub,
    const float* __restrict__ bup, const int* __restrict__ counts,
    const int* __restrict__ list, unsigned short* __restrict__ h) {
  const int e = blockIdx.z, mt = blockIdx.y, nt = blockIdx.x;
  const int cnt = counts[e];
  if (mt * 128 >= cnt) return;
  const int rem = min(128, cnt - mt * 128);
  const int* lst = list + e * TTOK + mt * 128;

  __shared__ __align__(16) char SM[18432];   // A bf16 8K | B bf16 8K; epilogue bounce 18K
  unsigned short* Sb = (unsigned short*)SM;

  const int tid = threadIdx.x;
  const int wave = tid >> 6, lane = tid & 63;
  const int srow = tid >> 2, cell = tid & 3;          // DMA: 4 thr/row (64B bf16 rows)

  const int tok0 = lst[min(srow, rem - 1)] >> 1;
  const int tok1 = lst[min(srow + 64, rem - 1)] >> 1;
  const unsigned short* a0 = xb + (size_t)tok0 * DDIM + cell * 8;
  const unsigned short* a1 = xb + (size_t)tok1 * DDIM + cell * 8;
  const unsigned short* b0 = wub + ((size_t)e * UDIM + nt * 128 + srow) * DDIM + cell * 8;
  const unsigned short* b1 = b0 + (size_t)64 * DDIM;

  const int wm = wave >> 1, wn = wave & 1;
  const int lane15 = lane & 15, quad = lane >> 4;
  const int abyte = (wm * 64 + lane15) * 64 + quad * 16;
  const int bbyte = 8192 + (wn * 64 + lane15) * 64 + quad * 16;

  float4v acc[4][4];
#pragma unroll
  for (int i = 0; i < 4; i++)
#pragma unroll
    for (int j = 0; j < 4; j++) acc[i][j] = (float4v){0.f, 0.f, 0.f, 0.f};

  for (int k0 = 0; k0 < DDIM; k0 += 32) {
    load_lds16(a0 + k0, SM + tid * 16);
    load_lds16(a1 + k0, SM + 4096 + tid * 16);
    load_lds16(b0 + k0, SM + 8192 + tid * 16);
    load_lds16(b1 + k0, SM + 12288 + tid * 16);
    __syncthreads();
    short8 af[4], bfr[4];
#pragma unroll
    for (int mi = 0; mi < 4; mi++) af[mi] = *(const short8*)(SM + abyte + mi * 1024);
#pragma unroll
    for (int ni = 0; ni < 4; ni++) bfr[ni] = *(const short8*)(SM + bbyte + ni * 1024);
#pragma unroll
    for (int mi = 0; mi < 4; mi++)
#pragma unroll
      for (int ni = 0; ni < 4; ni++)
        acc[mi][ni] = __builtin_amdgcn_mfma_f32_16x16x32_bf16(af[mi], bfr[ni], acc[mi][ni], 0, 0, 0);
    __syncthreads();
  }

  // epilogue: +bias, fast gelu -> bf16, LDS bounce, coalesced 16B stores
  const int ucol0 = nt * 128 + wn * 64;
  float bias[4];
#pragma unroll
  for (int ni = 0; ni < 4; ni++) bias[ni] = bup[e * UDIM + ucol0 + ni * 16 + lane15];
  const int row = tid >> 1, seg = tid & 1;
  const int opair = (row < rem) ? lst[row] : -1;
#pragma unroll
  for (int hh = 0; hh < 2; hh++) {
    if (wn == hh) {
#pragma unroll
      for (int mi = 0; mi < 4; mi++)
#pragma unroll
        for (int r = 0; r < 4; r++) {
          const int rl = wm * 64 + mi * 16 + quad * 4 + r;
#pragma unroll
          for (int ni = 0; ni < 4; ni++)
            Sb[rl * EPAD + ni * 16 + lane15] = f2bf(gelu_f(acc[mi][ni][r] + bias[ni]));
        }
    }
    __syncthreads();
    if (opair >= 0) {
      unsigned short* dst = h + (size_t)opair * UDIM + nt * 128 + hh * 64 + seg * 32;
      const unsigned short* src = Sb + row * EPAD + seg * 32;
#pragma unroll
      for (int c = 0; c < 4; c++) *(ushort8*)(dst + c * 8) = *(const ushort8*)(src + c * 8);
    }
    __syncthreads();
  }
}

// ======== bf16-weight stage B: partial[kc][pair] = h . Wdown (no bias/w) ========
__global__ __launch_bounds__(256, 4) void stage_down_b16(
    const unsigned short* __restrict__ h, const unsigned short* __restrict__ wdb,
    const int* __restrict__ counts, const int* __restrict__ list,
    unsigned short* __restrict__ part) {
  const int e = blockIdx.z, mt = blockIdx.y >> 1, kc = blockIdx.y & 1, nt = blockIdx.x;
  const int cnt = counts[e];
  if (mt * 128 >= cnt) return;
  const int rem = min(128, cnt - mt * 128);
  const int* lst = list + e * TTOK + mt * 128;

  __shared__ __align__(16) char SM[18432];
  unsigned short* Sb = (unsigned short*)SM;

  const int tid = threadIdx.x;
  const int wave = tid >> 6, lane = tid & 63;
  const int srow = tid >> 2, cell = tid & 3;

  const int pr0 = lst[min(srow, rem - 1)];
  const int pr1 = lst[min(srow + 64, rem - 1)];
  const unsigned short* a0 = h + (size_t)pr0 * UDIM + kc * KCH + cell * 8;
  const unsigned short* a1 = h + (size_t)pr1 * UDIM + kc * KCH + cell * 8;
  const unsigned short* b0 = wdb + ((size_t)e * DDIM + nt * 128 + srow) * UDIM + kc * KCH + cell * 8;
  const unsigned short* b1 = b0 + (size_t)64 * UDIM;

  const int wm = wave >> 1, wn = wave & 1;
  const int lane15 = lane & 15, quad = lane >> 4;
  const int abyte = (wm * 64 + lane15) * 64 + quad * 16;
  const int bbyte = 8192 + (wn * 64 + lane15) * 64 + quad * 16;

  float4v acc[4][4];
#pragma unroll
  for (int i = 0; i < 4; i++)
#pragma unroll
    for (int j = 0; j < 4; j++) acc[i][j] = (float4v){0.f, 0.f, 0.f, 0.f};

  for (int k0 = 0; k0 < KCH; k0 += 32) {
    load_lds16(a0 + k0, SM + tid * 16);
    load_lds16(a1 + k0, SM + 4096 + tid * 16);
    load_lds16(b0 + k0, SM + 8192 + tid * 16);
    load_lds16(b1 + k0, SM + 12288 + tid * 16);
    __syncthreads();
    short8 af[4], bfr[4];
#pragma unroll
    for (int mi = 0; mi < 4; mi++) af[mi] = *(const short8*)(SM + abyte + mi * 1024);
#pragma unroll
    for (int ni = 0; ni < 4; ni++) bfr[ni] = *(const short8*)(SM + bbyte + ni * 1024);
#pragma unroll
    for (int mi = 0; mi < 4; mi++)
#pragma unroll
      for (int ni = 0; ni < 4; ni++)
        acc[mi][ni] = __builtin_amdgcn_mfma_f32_16x16x32_bf16(af[mi], bfr[ni], acc[mi][ni], 0, 0, 0);
    __syncthreads();
  }

  const int row = tid >> 1, seg = tid & 1;
  const int opair = (row < rem) ? lst[row] : -1;
#pragma unroll
  for (int hh = 0; hh < 2; hh++) {
    if (wn == hh) {
#pragma unroll
      for (int mi = 0; mi < 4; mi++)
#pragma unroll
        for (int r = 0; r < 4; r++) {
          const int rl = wm * 64 + mi * 16 + quad * 4 + r;
#pragma unroll
          for (int ni = 0; ni < 4; ni++)
            Sb[rl * EPAD + ni * 16 + lane15] = f2bf(acc[mi][ni][r]);
        }
    }
    __syncthreads();
    if (opair >= 0) {
      unsigned short* dst = part + ((size_t)kc * NPAIR + opair) * DDIM + nt * 128 + hh * 64 + seg * 32;
      const unsigned short* src = Sb + row * EPAD + seg * 32;
#pragma unroll
      for (int c = 0; c < 4; c++) *(ushort8*)(dst + c * 8) = *(const ushort8*)(src + c * 8);
    }
    __syncthreads();
  }
}

// ======== fallback fp32-weight stages (verified path; used when ws too small) ========
__global__ __launch_bounds__(256, 3) void stage_up_k(
    const unsigned short* __restrict__ xb, const float* __restrict__ wu,
    const float* __restrict__ bup, const int* __restrict__ counts,
    const int* __restrict__ list, unsigned short* __restrict__ h) {
  const int e = blockIdx.z, mt = blockIdx.y, nt = blockIdx.x;
  const int cnt = counts[e];
  if (mt * 128 >= cnt) return;
  const int rem = min(128, cnt - mt * 128);
  const int* lst = list + e * TTOK + mt * 128;

  __shared__ __align__(16) char SM[24576];
  unsigned short* Sb = (unsigned short*)SM;

  const int tid = threadIdx.x;
  const int wave = tid >> 6, lane = tid & 63;
  const int srow = tid >> 2, cell = tid & 3;
  const int brow = tid >> 3;
  const int bswz = (tid & 7) ^ (brow & 7);

  const int tok0 = lst[min(srow, rem - 1)] >> 1;
  const int tok1 = lst[min(srow + 64, rem - 1)] >> 1;
  const unsigned short* a0 = xb + (size_t)tok0 * DDIM + cell * 8;
  const unsigned short* a1 = xb + (size_t)tok1 * DDIM + cell * 8;
  const float* bbase = wu + ((size_t)e * UDIM + nt * 128) * DDIM;
  const float* bsrc[4];
#pragma unroll
  for (int k = 0; k < 4; k++) bsrc[k] = bbase + (size_t)(brow + k * 32) * DDIM + bswz * 4;

  const int wm = wave >> 1, wn = wave & 1;
  const int lane15 = lane & 15, quad = lane >> 4;
  const int abyte = (wm * 64 + lane15) * 64 + quad * 16;
  const int p0 = (2 * quad) ^ (lane & 7);
  const int bbyte = 8192 + (wn * 64 + lane15) * 128;

  float4v acc[4][4];
#pragma unroll
  for (int i = 0; i < 4; i++)
#pragma unroll
    for (int j = 0; j < 4; j++) acc[i][j] = (float4v){0.f, 0.f, 0.f, 0.f};

  for (int k0 = 0; k0 < DDIM; k0 += 32) {
    load_lds16(a0 + k0, SM + tid * 16);
    load_lds16(a1 + k0, SM + 4096 + tid * 16);
#pragma unroll
    for (int k = 0; k < 4; k++) load_lds16(bsrc[k] + k0, SM + 8192 + k * 4096 + tid * 16);
    __syncthreads();
    short8 af[4], bfr[4];
#pragma unroll
    for (int mi = 0; mi < 4; mi++) af[mi] = *(const short8*)(SM + abyte + mi * 1024);
#pragma unroll
    for (int ni = 0; ni < 4; ni++) {
      const char* rb = SM + bbyte + ni * 2048;
      float4v f0 = *(const float4v*)(rb + p0 * 16);
      float4v f1 = *(const float4v*)(rb + (p0 ^ 1) * 16);
      bfr[ni] = cvt8(f0, f1);
    }
#pragma unroll
    for (int mi = 0; mi < 4; mi++)
#pragma unroll
      for (int ni = 0; ni < 4; ni++)
        acc[mi][ni] = __builtin_amdgcn_mfma_f32_16x16x32_bf16(af[mi], bfr[ni], acc[mi][ni], 0, 0, 0);
    __syncthreads();
  }

  const int ucol0 = nt * 128 + wn * 64;
  float bias[4];
#pragma unroll
  for (int ni = 0; ni < 4; ni++) bias[ni] = bup[e * UDIM + ucol0 + ni * 16 + lane15];
  const int row = tid >> 1, seg = tid & 1;
  const int opair = (row < rem) ? lst[row] : -1;
#pragma unroll
  for (int hh = 0; hh < 2; hh++) {
    if (wn == hh) {
#pragma unroll
      for (int mi = 0; mi < 4; mi++)
#pragma unroll
        for (int r = 0; r < 4; r++) {
          const int rl = wm * 64 + mi * 16 + quad * 4 + r;
#pragma unroll
          for (int ni = 0; ni < 4; ni++)
            Sb[rl * EPAD + ni * 16 + lane15] = f2bf(gelu_f(acc[mi][ni][r] + bias[ni]));
        }
    }
    __syncthreads();
    if (opair >= 0) {
      unsigned short* dst = h + (size_t)opair * UDIM + nt * 128 + hh * 64 + seg * 32;
      const unsigned short* src = Sb + row * EPAD + seg * 32;
#pragma unroll
      for (int c = 0; c < 4; c++) *(ushort8*)(dst + c * 8) = *(const ushort8*)(src + c * 8);
    }
    __syncthreads();
  }
}

template <bool PARTM>
__global__ __launch_bounds__(256, 3) void stage_down_k(
    const unsigned short* __restrict__ h, const float* __restrict__ wd,
    const float* __restrict__ bdn, const float* __restrict__ wpair,
    const int* __restrict__ counts, const int* __restrict__ list,
    unsigned short* __restrict__ part, float* __restrict__ out) {
  const int e = blockIdx.z, mt = blockIdx.y >> 1, kc = blockIdx.y & 1, nt = blockIdx.x;
  const int cnt = counts[e];
  if (mt * 128 >= cnt) return;
  const int rem = min(128, cnt - mt * 128);
  const int* lst = list + e * TTOK + mt * 128;

  __shared__ __align__(16) char SM[24576];
  unsigned short* Sb = (unsigned short*)SM;

  const int tid = threadIdx.x;
  const int wave = tid >> 6, lane = tid & 63;
  const int srow = tid >> 2, cell = tid & 3;
  const int brow = tid >> 3;
  const int bswz = (tid & 7) ^ (brow & 7);

  const int pr0 = lst[min(srow, rem - 1)];
  const int pr1 = lst[min(srow + 64, rem - 1)];
  const unsigned short* a0 = h + (size_t)pr0 * UDIM + kc * KCH + cell * 8;
  const unsigned short* a1 = h + (size_t)pr1 * UDIM + kc * KCH + cell * 8;
  const float* bbase = wd + ((size_t)e * DDIM + nt * 128) * UDIM + kc * KCH;
  const float* bsrc[4];
#pragma unroll
  for (int k = 0; k < 4; k++) bsrc[k] = bbase + (size_t)(brow + k * 32) * UDIM + bswz * 4;

  const int wm = wave >> 1, wn = wave & 1;
  const int lane15 = lane & 15, quad = lane >> 4;
  const int abyte = (wm * 64 + lane15) * 64 + quad * 16;
  const int p0 = (2 * quad) ^ (lane & 7);
  const int bbyte = 8192 + (wn * 64 + lane15) * 128;

  float4v acc[4][4];
#pragma unroll
  for (int i = 0; i < 4; i++)
#pragma unroll
    for (int j = 0; j < 4; j++) acc[i][j] = (float4v){0.f, 0.f, 0.f, 0.f};

  for (int k0 = 0; k0 < KCH; k0 += 32) {
    load_lds16(a0 + k0, SM + tid * 16);
    load_lds16(a1 + k0, SM + 4096 + tid * 16);
#pragma unroll
    for (int k = 0; k < 4; k++) load_lds16(bsrc[k] + k0, SM + 8192 + k * 4096 + tid * 16);
    __syncthreads();
    short8 af[4], bfr[4];
#pragma unroll
    for (int mi = 0; mi < 4; mi++) af[mi] = *(const short8*)(SM + abyte + mi * 1024);
#pragma unroll
    for (int ni = 0; ni < 4; ni++) {
      const char* rb = SM + bbyte + ni * 2048;
      float4v f0 = *(const float4v*)(rb + p0 * 16);
      float4v f1 = *(const float4v*)(rb + (p0 ^ 1) * 16);
      bfr[ni] = cvt8(f0, f1);
    }
#pragma unroll
    for (int mi = 0; mi < 4; mi++)
#pragma unroll
      for (int ni = 0; ni < 4; ni++)
        acc[mi][ni] = __builtin_amdgcn_mfma_f32_16x16x32_bf16(af[mi], bfr[ni], acc[mi][ni], 0, 0, 0);
    __syncthreads();
  }

  const int dcol0 = nt * 128 + wn * 64;
  if constexpr (PARTM) {
    const int row = tid >> 1, seg = tid & 1;
    const int opair = (row < rem) ? lst[row] : -1;
#pragma unroll
    for (int hh = 0; hh < 2; hh++) {
      if (wn == hh) {
#pragma unroll
        for (int mi = 0; mi < 4; mi++)
#pragma unroll
          for (int r = 0; r < 4; r++) {
            const int rl = wm * 64 + mi * 16 + quad * 4 + r;
#pragma unroll
            for (int ni = 0; ni < 4; ni++)
              Sb[rl * EPAD + ni * 16 + lane15] = f2bf(acc[mi][ni][r]);
          }
      }
      __syncthreads();
      if (opair >= 0) {
        unsigned short* dst = part + ((size_t)kc * NPAIR + opair) * DDIM + nt * 128 + hh * 64 + seg * 32;
        const unsigned short* src = Sb + row * EPAD + seg * 32;
#pragma unroll
        for (int c = 0; c < 4; c++) *(ushort8*)(dst + c * 8) = *(const ushort8*)(src + c * 8);
      }
      __syncthreads();
    }
  } else {
    float bias[4];
#pragma unroll
    for (int ni = 0; ni < 4; ni++)
      bias[ni] = (kc == 0) ? bdn[e * DDIM + dcol0 + ni * 16 + lane15] : 0.0f;
#pragma unroll
    for (int mi = 0; mi < 4; mi++)
#pragma unroll
      for (int r = 0; r < 4; r++) {
        const int mrow = wm * 64 + mi * 16 + quad * 4 + r;
        if (mrow < rem) {
          const int pair = lst[mrow];
          const float w = wpair[pair];
          float* orow = out + (size_t)(pair >> 1) * DDIM;
#pragma unroll
          for (int ni = 0; ni < 4; ni++)
            atomicAdd(&orow[dcol0 + ni * 16 + lane15], w * (acc[mi][ni][r] + bias[ni]));
        }
      }
  }
}

// ---------------- combine: out[t,d] = sum_j w_j * (bdn[e_j,d] + sum_kc part[kc,2t+j,d]) ----------------
__global__ void combine_kernel(const unsigned short* __restrict__ part,
                               const float* __restrict__ bdn,
                               const float* __restrict__ wpair,
                               const int* __restrict__ epair,
                               float* __restrict__ out) {
  const int idx = blockIdx.x * 256 + threadIdx.x;
  const int t = idx >> 7, c8 = (idx & 127) * 8;
  const size_t kstride = (size_t)NPAIR * DDIM;
  const unsigned short* pa = part + (size_t)(2 * t) * DDIM + c8;
  float s0[8], s1[8];
#pragma unroll
  for (int j = 0; j < 8; j++) { s0[j] = 0.f; s1[j] = 0.f; }
#pragma unroll
  for (int kc = 0; kc < KSPLIT; kc++) {
    ushort8 a = *(const ushort8*)(pa + kc * kstride);
    ushort8 b = *(const ushort8*)(pa + kc * kstride + DDIM);
#pragma unroll
    for (int j = 0; j < 8; j++) { s0[j] += bf2f(a[j]); s1[j] += bf2f(b[j]); }
  }
  const float w0 = wpair[2 * t], w1 = wpair[2 * t + 1];
  const int e0 = epair[2 * t], e1 = epair[2 * t + 1];
  const float* b0 = bdn + e0 * DDIM + c8;
  const float* b1 = bdn + e1 * DDIM + c8;
  float4v o[2];
#pragma unroll
  for (int half = 0; half < 2; half++)
#pragma unroll
    for (int j = 0; j < 4; j++) {
      const int jj = half * 4 + j;
      o[half][j] = w0 * (s0[jj] + b0[jj]) + w1 * (s1[jj] + b1[jj]);
    }
  float4v* dst = (float4v*)(out + (size_t)t * DDIM + c8);
  dst[0] = o[0]; dst[1] = o[1];
}

__global__ void zero_out_k(float4v* __restrict__ out) {
  const int tid = blockIdx.x * blockDim.x + threadIdx.x;
  const int O4 = TTOK * DDIM / 4;
  const int stride = gridDim.x * blockDim.x;
  for (int i = tid; i < O4; i += stride) out[i] = (float4v){0.f, 0.f, 0.f, 0.f};
}

extern "C" void kernel_launch(void* const* d_in, const int* in_sizes, int n_in,
                              void* d_out, int out_size, void* d_ws, size_t ws_size,
                              hipStream_t stream) {
  (void)in_sizes; (void)n_in; (void)out_size;
  const float* x        = (const float*)d_in[0];
  const float* w_router = (const float*)d_in[1];
  const float* w_up     = (const float*)d_in[2];
  const float* b_up     = (const float*)d_in[3];
  const float* w_down   = (const float*)d_in[4];
  const float* b_down   = (const float*)d_in[5];
  float* out = (float*)d_out;

  char* ws = (char*)d_ws;
  size_t off = 0;
  auto take = [&](size_t b) { size_t o = off; off = (off + b + 255) & ~(size_t)255; return o; };
  unsigned short* h  = (unsigned short*)(ws + take((size_t)NPAIR * UDIM * 2));   // 64 MiB
  unsigned short* xb = (unsigned short*)(ws + take((size_t)TTOK * DDIM * 2));    // 8 MiB
  int* counts        = (int*)(ws + take(NEXP * 4));
  int* list          = (int*)(ws + take((size_t)NEXP * TTOK * 4));
  float* wpair       = (float*)(ws + take((size_t)NPAIR * 4));
  int* epair         = (int*)(ws + take((size_t)NPAIR * 4));
  size_t part_off    = take((size_t)KSPLIT * NPAIR * DDIM * 2);                  // 32 MiB
  const bool partmode = ws_size >= off;
  size_t wub_off     = take((size_t)NEXP * UDIM * DDIM * 2);                     // 64 MiB
  size_t wdb_off     = take((size_t)NEXP * DDIM * UDIM * 2);                     // 64 MiB
  const bool bf16mode = ws_size >= off;

  hipMemsetAsync(counts, 0, NEXP * 4, stream);

  if (bf16mode) {
    unsigned short* part = (unsigned short*)(ws + part_off);
    unsigned short* wub  = (unsigned short*)(ws + wub_off);
    unsigned short* wdb  = (unsigned short*)(ws + wdb_off);
    // router (1024 blocks) + fp32->bf16 weight conversion (2048 blocks), fused
    prep_kernel<<<TTOK / 4 + 2048, 256, 0, stream>>>(
        x, w_router, counts, list, wpair, epair, xb, w_up, w_down, wub, wdb);
    stage_up_b16<<<dim3(UDIM / 128, 32, NEXP), 256, 0, stream>>>(
        xb, wub, b_up, counts, list, h);
    stage_down_b16<<<dim3(DDIM / 128, 32 * KSPLIT, NEXP), 256, 0, stream>>>(
        h, wdb, counts, list, part);
    combine_kernel<<<TTOK * DDIM / 8 / 256, 256, 0, stream>>>(part, b_down, wpair, epair, out);
  } else {
    router_kernel<<<TTOK / 4, 256, 0, stream>>>(x, w_router, counts, list, wpair, epair, xb);
    stage_up_k<<<dim3(UDIM / 128, 32, NEXP), 256, 0, stream>>>(xb, w_up, b_up, counts, list, h);
    if (partmode) {
      unsigned short* part = (unsigned short*)(ws + part_off);
      stage_down_k<true><<<dim3(DDIM / 128, 32 * KSPLIT, NEXP), 256, 0, stream>>>(
          h, w_down, b_down, wpair, counts, list, part, out);
      combine_kernel<<<TTOK * DDIM / 8 / 256, 256, 0, stream>>>(part, b_down, wpair, epair, out);
    } else {
      zero_out_k<<<1024, 256, 0, stream>>>((float4v*)out);
      stage_down_k<false><<<dim3(DDIM / 128, 32 * KSPLIT, NEXP), 256, 0, stream>>>(
          h, w_down, b_down, wpair, counts, list, (unsigned short*)nullptr, out);
    }
  }
}

// Round 2
// 602.927 us; speedup vs baseline: 1.1077x; 1.0813x over previous
//
#include <hip/hip_runtime.h>
#include <hip/hip_bf16.h>
#include <stdint.h>
#include <math.h>

// Problem constants (B=2,S=2048 -> T=4096 tokens), D=1024, U=4096, E=8, K=2
#define TTOK 4096
#define DDIM 1024
#define UDIM 4096
#define NEXP 8
#define KSPLIT 2            // split-K chunks for stage_down (K=4096 -> 2x2048)
#define KCH   (UDIM / KSPLIT)
#define NPAIR (TTOK * 2)
#define EPAD 72             // epilogue LDS bounce row stride (shorts)
#define CPAD 32             // counter padding (ints) -> one counter per 128B line
#define RBLK 128            // router blocks in prep (32 tokens each)
#define CBLK 2048           // conversion blocks in prep

using float4v = __attribute__((ext_vector_type(4))) float;
using short8  = __attribute__((ext_vector_type(8))) short;
using ushort8 = __attribute__((ext_vector_type(8))) unsigned short;
using ushort4v = __attribute__((ext_vector_type(4))) unsigned short;

__device__ __forceinline__ unsigned short f2bf(float f) {
  union { float f; unsigned u; } v; v.f = f;
  unsigned r = v.u + 0x7FFFu + ((v.u >> 16) & 1u);  // RNE
  return (unsigned short)(r >> 16);
}
__device__ __forceinline__ float bf2f(unsigned short u) {
  union { unsigned u; float f; } v; v.u = ((unsigned)u) << 16;
  return v.f;
}
__device__ __forceinline__ void load_lds16(const void* g, void* l) {
  __builtin_amdgcn_global_load_lds(
      (const __attribute__((address_space(1))) unsigned int*)g,
      (__attribute__((address_space(3))) unsigned int*)l, 16, 0, 0);
}
// 8 fp32 -> 8 bf16 (RNE), packed
__device__ __forceinline__ short8 cvt8(const float4v a, const float4v b) {
  union { __hip_bfloat162 h[4]; short8 s; } u;
  u.h[0] = __float22bfloat162_rn(make_float2(a[0], a[1]));
  u.h[1] = __float22bfloat162_rn(make_float2(a[2], a[3]));
  u.h[2] = __float22bfloat162_rn(make_float2(b[0], b[1]));
  u.h[3] = __float22bfloat162_rn(make_float2(b[2], b[3]));
  return u.s;
}
// tanh-form gelu: v * sigmoid(2*0.797885*(v+0.044715 v^3)); NaN-safe at +-inf of exp
__device__ __forceinline__ float gelu_f(float v) {
  float u = v * (0.7978845608f + 0.0356774081f * v * v);
  float ex = __expf(2.0f * u);
  return v * (1.0f - 1.0f / (1.0f + ex));
}

// ---------------- fallback router (per-token atomics, padded counters) ----------------
__global__ void router_kernel(const float* __restrict__ x,
                              const float* __restrict__ wr,
                              int* __restrict__ counts, int* __restrict__ list,
                              float* __restrict__ wpair, int* __restrict__ epair,
                              unsigned short* __restrict__ xb) {
  const int t = blockIdx.x * 4 + (threadIdx.x >> 6);
  const int lane = threadIdx.x & 63;
  float acc[NEXP];
#pragma unroll
  for (int e = 0; e < NEXP; e++) acc[e] = 0.0f;
  const float* xr = x + (size_t)t * DDIM;
  unsigned short* xbr = xb + (size_t)t * DDIM;
  for (int d = lane; d < DDIM; d += 64) {
    float xv = xr[d];
    xbr[d] = f2bf(xv);
#pragma unroll
    for (int e = 0; e < NEXP; e++) acc[e] += xv * wr[e * DDIM + d];
  }
#pragma unroll
  for (int e = 0; e < NEXP; e++) {
#pragma unroll
    for (int off = 32; off > 0; off >>= 1) acc[e] += __shfl_xor(acc[e], off, 64);
  }
  if (lane == 0) {
    int e0 = 0; float l0 = acc[0];
    for (int e = 1; e < NEXP; e++) if (acc[e] > l0) { l0 = acc[e]; e0 = e; }
    int e1 = -1; float l1 = -3.4e38f;
    for (int e = 0; e < NEXP; e++) if (e != e0 && acc[e] > l1) { l1 = acc[e]; e1 = e; }
    float s1 = expf(l1 - l0);
    float inv = 1.0f / (1.0f + s1);
    int p0 = atomicAdd(&counts[e0 * CPAD], 1);
    list[e0 * TTOK + p0] = 2 * t;
    wpair[2 * t] = inv;  epair[2 * t] = e0;
    int p1 = atomicAdd(&counts[e1 * CPAD], 1);
    list[e1 * TTOK + p1] = 2 * t + 1;
    wpair[2 * t + 1] = s1 * inv;  epair[2 * t + 1] = e1;
  }
}

// ---------------- prep: router via block-aggregated counting sort (blocks 0..RBLK-1)
// + weight fp32->bf16 conversion, contiguous chunks, fully unrolled (rest) ----------------
__global__ void prep_kernel(const float* __restrict__ x, const float* __restrict__ wr,
                            int* __restrict__ counts, int* __restrict__ list,
                            float* __restrict__ wpair, int* __restrict__ epair,
                            unsigned short* __restrict__ xb,
                            const float* __restrict__ wu, const float* __restrict__ wd,
                            unsigned short* __restrict__ wub, unsigned short* __restrict__ wdb) {
  __shared__ int sE0[32], sE1[32];
  const int bid = blockIdx.x;
  const int tid = threadIdx.x;

  if (bid < RBLK) {
    // ---- router: 32 tokens/block, 8 tokens per wave ----
    const int wave = tid >> 6, lane = tid & 63;
#pragma unroll 1
    for (int j = 0; j < 8; j++) {
      const int slot = wave * 8 + j;
      const int t = bid * 32 + slot;
      float acc[NEXP];
#pragma unroll
      for (int e = 0; e < NEXP; e++) acc[e] = 0.0f;
      const float* xr = x + (size_t)t * DDIM;
      unsigned short* xbr = xb + (size_t)t * DDIM;
#pragma unroll
      for (int it = 0; it < 4; it++) {
        const int d = it * 256 + lane * 4;
        float4v xv = *(const float4v*)(xr + d);
        ushort4v xo;
#pragma unroll
        for (int c = 0; c < 4; c++) xo[c] = f2bf(xv[c]);
        *(ushort4v*)(xbr + d) = xo;
#pragma unroll
        for (int e = 0; e < NEXP; e++) {
          float4v wv = *(const float4v*)(wr + e * DDIM + d);
          acc[e] += xv[0] * wv[0] + xv[1] * wv[1] + xv[2] * wv[2] + xv[3] * wv[3];
        }
      }
#pragma unroll
      for (int e = 0; e < NEXP; e++) {
#pragma unroll
        for (int off = 32; off > 0; off >>= 1) acc[e] += __shfl_xor(acc[e], off, 64);
      }
      if (lane == 0) {
        int e0 = 0; float l0 = acc[0];
        for (int e = 1; e < NEXP; e++) if (acc[e] > l0) { l0 = acc[e]; e0 = e; }
        int e1 = -1; float l1 = -3.4e38f;
        for (int e = 0; e < NEXP; e++) if (e != e0 && acc[e] > l1) { l1 = acc[e]; e1 = e; }
        float s1 = expf(l1 - l0);
        float inv = 1.0f / (1.0f + s1);
        wpair[2 * t] = inv;          epair[2 * t] = e0;
        wpair[2 * t + 1] = s1 * inv; epair[2 * t + 1] = e1;
        sE0[slot] = e0;  sE1[slot] = e1;
      }
    }
    __syncthreads();
    // ---- 8 threads: per-expert count, one padded atomic, deterministic scatter ----
    if (tid < NEXP) {
      const int e = tid;
      int cnt = 0;
#pragma unroll
      for (int s = 0; s < 32; s++) cnt += (sE0[s] == e) + (sE1[s] == e);
      int r = atomicAdd(&counts[e * CPAD], cnt);
      int* le = list + e * TTOK;
#pragma unroll 1
      for (int s = 0; s < 32; s++) {
        const int p = 2 * (bid * 32 + s);
        if (sE0[s] == e) le[r++] = p;
        if (sE1[s] == e) le[r++] = p + 1;
      }
    }
    return;
  }

  // ---- conversion: contiguous 4096-group chunk per block, compile-time 16-iter loop ----
  const int cb = bid - RBLK;
  const float* s; unsigned short* d;
  size_t i0;
  if (cb < CBLK / 2) { s = wu; d = wub; i0 = (size_t)cb * 4096; }
  else               { s = wd; d = wdb; i0 = (size_t)(cb - CBLK / 2) * 4096; }
#pragma unroll
  for (int it = 0; it < 16; it++) {
    const size_t i = i0 + (size_t)it * 256 + tid;
    float4v lo = *(const float4v*)(s + i * 8);
    float4v hi = *(const float4v*)(s + i * 8 + 4);
    *(short8*)(d + i * 8) = cvt8(lo, hi);
  }
}

// ======== bf16-weight stage A: h[pair,u] = gelu(x . Wup + bup). m97 K-loop:
// 4 global_load_lds (16KB), 8 ds_read_b128, 16 MFMA per K-step. ========
__global__ __launch_bounds__(256, 4) void stage_up_b16(
    const unsigned short* __restrict__ xb, const unsigned short* __restrict__ wub,
    const float* __restrict__ bup, const int* __restrict__ counts,
    const int* __restrict__ list, unsigned short* __restrict__ h) {
  const int e = blockIdx.z, mt = blockIdx.y, nt = blockIdx.x;
  const int cnt = counts[e * CPAD];
  if (mt * 128 >= cnt) return;
  const int rem = min(128, cnt - mt * 128);
  const int* lst = list + e * TTOK + mt * 128;

  __shared__ __align__(16) char SM[18432];   // A bf16 8K | B bf16 8K; epilogue bounce 18K
  unsigned short* Sb = (unsigned short*)SM;

  const int tid = threadIdx.x;
  const int wave = tid >> 6, lane = tid & 63;
  const int srow = tid >> 2, cell = tid & 3;          // DMA: 4 thr/row (64B bf16 rows)

  const int tok0 = lst[min(srow, rem - 1)] >> 1;
  const int tok1 = lst[min(srow + 64, rem - 1)] >> 1;
  const unsigned short* a0 = xb + (size_t)tok0 * DDIM + cell * 8;
  const unsigned short* a1 = xb + (size_t)tok1 * DDIM + cell * 8;
  const unsigned short* b0 = wub + ((size_t)e * UDIM + nt * 128 + srow) * DDIM + cell * 8;
  const unsigned short* b1 = b0 + (size_t)64 * DDIM;

  const int wm = wave >> 1, wn = wave & 1;
  const int lane15 = lane & 15, quad = lane >> 4;
  const int abyte = (wm * 64 + lane15) * 64 + quad * 16;
  const int bbyte = 8192 + (wn * 64 + lane15) * 64 + quad * 16;

  float4v acc[4][4];
#pragma unroll
  for (int i = 0; i < 4; i++)
#pragma unroll
    for (int j = 0; j < 4; j++) acc[i][j] = (float4v){0.f, 0.f, 0.f, 0.f};

  for (int k0 = 0; k0 < DDIM; k0 += 32) {
    load_lds16(a0 + k0, SM + tid * 16);
    load_lds16(a1 + k0, SM + 4096 + tid * 16);
    load_lds16(b0 + k0, SM + 8192 + tid * 16);
    load_lds16(b1 + k0, SM + 12288 + tid * 16);
    __syncthreads();
    short8 af[4], bfr[4];
#pragma unroll
    for (int mi = 0; mi < 4; mi++) af[mi] = *(const short8*)(SM + abyte + mi * 1024);
#pragma unroll
    for (int ni = 0; ni < 4; ni++) bfr[ni] = *(const short8*)(SM + bbyte + ni * 1024);
#pragma unroll
    for (int mi = 0; mi < 4; mi++)
#pragma unroll
      for (int ni = 0; ni < 4; ni++)
        acc[mi][ni] = __builtin_amdgcn_mfma_f32_16x16x32_bf16(af[mi], bfr[ni], acc[mi][ni], 0, 0, 0);
    __syncthreads();
  }

  // epilogue: +bias, fast gelu -> bf16, LDS bounce, coalesced 16B stores
  const int ucol0 = nt * 128 + wn * 64;
  float bias[4];
#pragma unroll
  for (int ni = 0; ni < 4; ni++) bias[ni] = bup[e * UDIM + ucol0 + ni * 16 + lane15];
  const int row = tid >> 1, seg = tid & 1;
  const int opair = (row < rem) ? lst[row] : -1;
#pragma unroll
  for (int hh = 0; hh < 2; hh++) {
    if (wn == hh) {
#pragma unroll
      for (int mi = 0; mi < 4; mi++)
#pragma unroll
        for (int r = 0; r < 4; r++) {
          const int rl = wm * 64 + mi * 16 + quad * 4 + r;
#pragma unroll
          for (int ni = 0; ni < 4; ni++)
            Sb[rl * EPAD + ni * 16 + lane15] = f2bf(gelu_f(acc[mi][ni][r] + bias[ni]));
        }
    }
    __syncthreads();
    if (opair >= 0) {
      unsigned short* dst = h + (size_t)opair * UDIM + nt * 128 + hh * 64 + seg * 32;
      const unsigned short* src = Sb + row * EPAD + seg * 32;
#pragma unroll
      for (int c = 0; c < 4; c++) *(ushort8*)(dst + c * 8) = *(const ushort8*)(src + c * 8);
    }
    __syncthreads();
  }
}

// ======== bf16-weight stage B: partial[kc][pair] = h . Wdown (no bias/w) ========
__global__ __launch_bounds__(256, 4) void stage_down_b16(
    const unsigned short* __restrict__ h, const unsigned short* __restrict__ wdb,
    const int* __restrict__ counts, const int* __restrict__ list,
    unsigned short* __restrict__ part) {
  const int e = blockIdx.z, mt = blockIdx.y >> 1, kc = blockIdx.y & 1, nt = blockIdx.x;
  const int cnt = counts[e * CPAD];
  if (mt * 128 >= cnt) return;
  const int rem = min(128, cnt - mt * 128);
  const int* lst = list + e * TTOK + mt * 128;

  __shared__ __align__(16) char SM[18432];
  unsigned short* Sb = (unsigned short*)SM;

  const int tid = threadIdx.x;
  const int wave = tid >> 6, lane = tid & 63;
  const int srow = tid >> 2, cell = tid & 3;

  const int pr0 = lst[min(srow, rem - 1)];
  const int pr1 = lst[min(srow + 64, rem - 1)];
  const unsigned short* a0 = h + (size_t)pr0 * UDIM + kc * KCH + cell * 8;
  const unsigned short* a1 = h + (size_t)pr1 * UDIM + kc * KCH + cell * 8;
  const unsigned short* b0 = wdb + ((size_t)e * DDIM + nt * 128 + srow) * UDIM + kc * KCH + cell * 8;
  const unsigned short* b1 = b0 + (size_t)64 * UDIM;

  const int wm = wave >> 1, wn = wave & 1;
  const int lane15 = lane & 15, quad = lane >> 4;
  const int abyte = (wm * 64 + lane15) * 64 + quad * 16;
  const int bbyte = 8192 + (wn * 64 + lane15) * 64 + quad * 16;

  float4v acc[4][4];
#pragma unroll
  for (int i = 0; i < 4; i++)
#pragma unroll
    for (int j = 0; j < 4; j++) acc[i][j] = (float4v){0.f, 0.f, 0.f, 0.f};

  for (int k0 = 0; k0 < KCH; k0 += 32) {
    load_lds16(a0 + k0, SM + tid * 16);
    load_lds16(a1 + k0, SM + 4096 + tid * 16);
    load_lds16(b0 + k0, SM + 8192 + tid * 16);
    load_lds16(b1 + k0, SM + 12288 + tid * 16);
    __syncthreads();
    short8 af[4], bfr[4];
#pragma unroll
    for (int mi = 0; mi < 4; mi++) af[mi] = *(const short8*)(SM + abyte + mi * 1024);
#pragma unroll
    for (int ni = 0; ni < 4; ni++) bfr[ni] = *(const short8*)(SM + bbyte + ni * 1024);
#pragma unroll
    for (int mi = 0; mi < 4; mi++)
#pragma unroll
      for (int ni = 0; ni < 4; ni++)
        acc[mi][ni] = __builtin_amdgcn_mfma_f32_16x16x32_bf16(af[mi], bfr[ni], acc[mi][ni], 0, 0, 0);
    __syncthreads();
  }

  const int row = tid >> 1, seg = tid & 1;
  const int opair = (row < rem) ? lst[row] : -1;
#pragma unroll
  for (int hh = 0; hh < 2; hh++) {
    if (wn == hh) {
#pragma unroll
      for (int mi = 0; mi < 4; mi++)
#pragma unroll
        for (int r = 0; r < 4; r++) {
          const int rl = wm * 64 + mi * 16 + quad * 4 + r;
#pragma unroll
          for (int ni = 0; ni < 4; ni++)
            Sb[rl * EPAD + ni * 16 + lane15] = f2bf(acc[mi][ni][r]);
        }
    }
    __syncthreads();
    if (opair >= 0) {
      unsigned short* dst = part + ((size_t)kc * NPAIR + opair) * DDIM + nt * 128 + hh * 64 + seg * 32;
      const unsigned short* src = Sb + row * EPAD + seg * 32;
#pragma unroll
      for (int c = 0; c < 4; c++) *(ushort8*)(dst + c * 8) = *(const ushort8*)(src + c * 8);
    }
    __syncthreads();
  }
}

// ======== fallback fp32-weight stages (verified path; used when ws too small) ========
__global__ __launch_bounds__(256, 3) void stage_up_k(
    const unsigned short* __restrict__ xb, const float* __restrict__ wu,
    const float* __restrict__ bup, const int* __restrict__ counts,
    const int* __restrict__ list, unsigned short* __restrict__ h) {
  const int e = blockIdx.z, mt = blockIdx.y, nt = blockIdx.x;
  const int cnt = counts[e * CPAD];
  if (mt * 128 >= cnt) return;
  const int rem = min(128, cnt - mt * 128);
  const int* lst = list + e * TTOK + mt * 128;

  __shared__ __align__(16) char SM[24576];
  unsigned short* Sb = (unsigned short*)SM;

  const int tid = threadIdx.x;
  const int wave = tid >> 6, lane = tid & 63;
  const int srow = tid >> 2, cell = tid & 3;
  const int brow = tid >> 3;
  const int bswz = (tid & 7) ^ (brow & 7);

  const int tok0 = lst[min(srow, rem - 1)] >> 1;
  const int tok1 = lst[min(srow + 64, rem - 1)] >> 1;
  const unsigned short* a0 = xb + (size_t)tok0 * DDIM + cell * 8;
  const unsigned short* a1 = xb + (size_t)tok1 * DDIM + cell * 8;
  const float* bbase = wu + ((size_t)e * UDIM + nt * 128) * DDIM;
  const float* bsrc[4];
#pragma unroll
  for (int k = 0; k < 4; k++) bsrc[k] = bbase + (size_t)(brow + k * 32) * DDIM + bswz * 4;

  const int wm = wave >> 1, wn = wave & 1;
  const int lane15 = lane & 15, quad = lane >> 4;
  const int abyte = (wm * 64 + lane15) * 64 + quad * 16;
  const int p0 = (2 * quad) ^ (lane & 7);
  const int bbyte = 8192 + (wn * 64 + lane15) * 128;

  float4v acc[4][4];
#pragma unroll
  for (int i = 0; i < 4; i++)
#pragma unroll
    for (int j = 0; j < 4; j++) acc[i][j] = (float4v){0.f, 0.f, 0.f, 0.f};

  for (int k0 = 0; k0 < DDIM; k0 += 32) {
    load_lds16(a0 + k0, SM + tid * 16);
    load_lds16(a1 + k0, SM + 4096 + tid * 16);
#pragma unroll
    for (int k = 0; k < 4; k++) load_lds16(bsrc[k] + k0, SM + 8192 + k * 4096 + tid * 16);
    __syncthreads();
    short8 af[4], bfr[4];
#pragma unroll
    for (int mi = 0; mi < 4; mi++) af[mi] = *(const short8*)(SM + abyte + mi * 1024);
#pragma unroll
    for (int ni = 0; ni < 4; ni++) {
      const char* rb = SM + bbyte + ni * 2048;
      float4v f0 = *(const float4v*)(rb + p0 * 16);
      float4v f1 = *(const float4v*)(rb + (p0 ^ 1) * 16);
      bfr[ni] = cvt8(f0, f1);
    }
#pragma unroll
    for (int mi = 0; mi < 4; mi++)
#pragma unroll
      for (int ni = 0; ni < 4; ni++)
        acc[mi][ni] = __builtin_amdgcn_mfma_f32_16x16x32_bf16(af[mi], bfr[ni], acc[mi][ni], 0, 0, 0);
    __syncthreads();
  }

  const int ucol0 = nt * 128 + wn * 64;
  float bias[4];
#pragma unroll
  for (int ni = 0; ni < 4; ni++) bias[ni] = bup[e * UDIM + ucol0 + ni * 16 + lane15];
  const int row = tid >> 1, seg = tid & 1;
  const int opair = (row < rem) ? lst[row] : -1;
#pragma unroll
  for (int hh = 0; hh < 2; hh++) {
    if (wn == hh) {
#pragma unroll
      for (int mi = 0; mi < 4; mi++)
#pragma unroll
        for (int r = 0; r < 4; r++) {
          const int rl = wm * 64 + mi * 16 + quad * 4 + r;
#pragma unroll
          for (int ni = 0; ni < 4; ni++)
            Sb[rl * EPAD + ni * 16 + lane15] = f2bf(gelu_f(acc[mi][ni][r] + bias[ni]));
        }
    }
    __syncthreads();
    if (opair >= 0) {
      unsigned short* dst = h + (size_t)opair * UDIM + nt * 128 + hh * 64 + seg * 32;
      const unsigned short* src = Sb + row * EPAD + seg * 32;
#pragma unroll
      for (int c = 0; c < 4; c++) *(ushort8*)(dst + c * 8) = *(const ushort8*)(src + c * 8);
    }
    __syncthreads();
  }
}

template <bool PARTM>
__global__ __launch_bounds__(256, 3) void stage_down_k(
    const unsigned short* __restrict__ h, const float* __restrict__ wd,
    const float* __restrict__ bdn, const float* __restrict__ wpair,
    const int* __restrict__ counts, const int* __restrict__ list,
    unsigned short* __restrict__ part, float* __restrict__ out) {
  const int e = blockIdx.z, mt = blockIdx.y >> 1, kc = blockIdx.y & 1, nt = blockIdx.x;
  const int cnt = counts[e * CPAD];
  if (mt * 128 >= cnt) return;
  const int rem = min(128, cnt - mt * 128);
  const int* lst = list + e * TTOK + mt * 128;

  __shared__ __align__(16) char SM[24576];
  unsigned short* Sb = (unsigned short*)SM;

  const int tid = threadIdx.x;
  const int wave = tid >> 6, lane = tid & 63;
  const int srow = tid >> 2, cell = tid & 3;
  const int brow = tid >> 3;
  const int bswz = (tid & 7) ^ (brow & 7);

  const int pr0 = lst[min(srow, rem - 1)];
  const int pr1 = lst[min(srow + 64, rem - 1)];
  const unsigned short* a0 = h + (size_t)pr0 * UDIM + kc * KCH + cell * 8;
  const unsigned short* a1 = h + (size_t)pr1 * UDIM + kc * KCH + cell * 8;
  const float* bbase = wd + ((size_t)e * DDIM + nt * 128) * UDIM + kc * KCH;
  const float* bsrc[4];
#pragma unroll
  for (int k = 0; k < 4; k++) bsrc[k] = bbase + (size_t)(brow + k * 32) * UDIM + bswz * 4;

  const int wm = wave >> 1, wn = wave & 1;
  const int lane15 = lane & 15, quad = lane >> 4;
  const int abyte = (wm * 64 + lane15) * 64 + quad * 16;
  const int p0 = (2 * quad) ^ (lane & 7);
  const int bbyte = 8192 + (wn * 64 + lane15) * 128;

  float4v acc[4][4];
#pragma unroll
  for (int i = 0; i < 4; i++)
#pragma unroll
    for (int j = 0; j < 4; j++) acc[i][j] = (float4v){0.f, 0.f, 0.f, 0.f};

  for (int k0 = 0; k0 < KCH; k0 += 32) {
    load_lds16(a0 + k0, SM + tid * 16);
    load_lds16(a1 + k0, SM + 4096 + tid * 16);
#pragma unroll
    for (int k = 0; k < 4; k++) load_lds16(bsrc[k] + k0, SM + 8192 + k * 4096 + tid * 16);
    __syncthreads();
    short8 af[4], bfr[4];
#pragma unroll
    for (int mi = 0; mi < 4; mi++) af[mi] = *(const short8*)(SM + abyte + mi * 1024);
#pragma unroll
    for (int ni = 0; ni < 4; ni++) {
      const char* rb = SM + bbyte + ni * 2048;
      float4v f0 = *(const float4v*)(rb + p0 * 16);
      float4v f1 = *(const float4v*)(rb + (p0 ^ 1) * 16);
      bfr[ni] = cvt8(f0, f1);
    }
#pragma unroll
    for (int mi = 0; mi < 4; mi++)
#pragma unroll
      for (int ni = 0; ni < 4; ni++)
        acc[mi][ni] = __builtin_amdgcn_mfma_f32_16x16x32_bf16(af[mi], bfr[ni], acc[mi][ni], 0, 0, 0);
    __syncthreads();
  }

  const int dcol0 = nt * 128 + wn * 64;
  if constexpr (PARTM) {
    const int row = tid >> 1, seg = tid & 1;
    const int opair = (row < rem) ? lst[row] : -1;
#pragma unroll
    for (int hh = 0; hh < 2; hh++) {
      if (wn == hh) {
#pragma unroll
        for (int mi = 0; mi < 4; mi++)
#pragma unroll
          for (int r = 0; r < 4; r++) {
            const int rl = wm * 64 + mi * 16 + quad * 4 + r;
#pragma unroll
            for (int ni = 0; ni < 4; ni++)
              Sb[rl * EPAD + ni * 16 + lane15] = f2bf(acc[mi][ni][r]);
          }
      }
      __syncthreads();
      if (opair >= 0) {
        unsigned short* dst = part + ((size_t)kc * NPAIR + opair) * DDIM + nt * 128 + hh * 64 + seg * 32;
        const unsigned short* src = Sb + row * EPAD + seg * 32;
#pragma unroll
        for (int c = 0; c < 4; c++) *(ushort8*)(dst + c * 8) = *(const ushort8*)(src + c * 8);
      }
      __syncthreads();
    }
  } else {
    float bias[4];
#pragma unroll
    for (int ni = 0; ni < 4; ni++)
      bias[ni] = (kc == 0) ? bdn[e * DDIM + dcol0 + ni * 16 + lane15] : 0.0f;
#pragma unroll
    for (int mi = 0; mi < 4; mi++)
#pragma unroll
      for (int r = 0; r < 4; r++) {
        const int mrow = wm * 64 + mi * 16 + quad * 4 + r;
        if (mrow < rem) {
          const int pair = lst[mrow];
          const float w = wpair[pair];
          float* orow = out + (size_t)(pair >> 1) * DDIM;
#pragma unroll
          for (int ni = 0; ni < 4; ni++)
            atomicAdd(&orow[dcol0 + ni * 16 + lane15], w * (acc[mi][ni][r] + bias[ni]));
        }
      }
  }
}

// ---------------- combine: out[t,d] = sum_j w_j * (bdn[e_j,d] + sum_kc part[kc,2t+j,d]) ----------------
__global__ void combine_kernel(const unsigned short* __restrict__ part,
                               const float* __restrict__ bdn,
                               const float* __restrict__ wpair,
                               const int* __restrict__ epair,
                               float* __restrict__ out) {
  const int idx = blockIdx.x * 256 + threadIdx.x;
  const int t = idx >> 7, c8 = (idx & 127) * 8;
  const size_t kstride = (size_t)NPAIR * DDIM;
  const unsigned short* pa = part + (size_t)(2 * t) * DDIM + c8;
  float s0[8], s1[8];
#pragma unroll
  for (int j = 0; j < 8; j++) { s0[j] = 0.f; s1[j] = 0.f; }
#pragma unroll
  for (int kc = 0; kc < KSPLIT; kc++) {
    ushort8 a = *(const ushort8*)(pa + kc * kstride);
    ushort8 b = *(const ushort8*)(pa + kc * kstride + DDIM);
#pragma unroll
    for (int j = 0; j < 8; j++) { s0[j] += bf2f(a[j]); s1[j] += bf2f(b[j]); }
  }
  const float w0 = wpair[2 * t], w1 = wpair[2 * t + 1];
  const int e0 = epair[2 * t], e1 = epair[2 * t + 1];
  const float* b0 = bdn + e0 * DDIM + c8;
  const float* b1 = bdn + e1 * DDIM + c8;
  float4v o[2];
#pragma unroll
  for (int half = 0; half < 2; half++)
#pragma unroll
    for (int j = 0; j < 4; j++) {
      const int jj = half * 4 + j;
      o[half][j] = w0 * (s0[jj] + b0[jj]) + w1 * (s1[jj] + b1[jj]);
    }
  float4v* dst = (float4v*)(out + (size_t)t * DDIM + c8);
  dst[0] = o[0]; dst[1] = o[1];
}

__global__ void zero_out_k(float4v* __restrict__ out) {
  const int tid = blockIdx.x * blockDim.x + threadIdx.x;
  const int O4 = TTOK * DDIM / 4;
  const int stride = gridDim.x * blockDim.x;
  for (int i = tid; i < O4; i += stride) out[i] = (float4v){0.f, 0.f, 0.f, 0.f};
}

extern "C" void kernel_launch(void* const* d_in, const int* in_sizes, int n_in,
                              void* d_out, int out_size, void* d_ws, size_t ws_size,
                              hipStream_t stream) {
  (void)in_sizes; (void)n_in; (void)out_size;
  const float* x        = (const float*)d_in[0];
  const float* w_router = (const float*)d_in[1];
  const float* w_up     = (const float*)d_in[2];
  const float* b_up     = (const float*)d_in[3];
  const float* w_down   = (const float*)d_in[4];
  const float* b_down   = (const float*)d_in[5];
  float* out = (float*)d_out;

  char* ws = (char*)d_ws;
  size_t off = 0;
  auto take = [&](size_t b) { size_t o = off; off = (off + b + 255) & ~(size_t)255; return o; };
  unsigned short* h  = (unsigned short*)(ws + take((size_t)NPAIR * UDIM * 2));   // 64 MiB
  unsigned short* xb = (unsigned short*)(ws + take((size_t)TTOK * DDIM * 2));    // 8 MiB
  int* counts        = (int*)(ws + take(NEXP * CPAD * 4));
  int* list          = (int*)(ws + take((size_t)NEXP * TTOK * 4));
  float* wpair       = (float*)(ws + take((size_t)NPAIR * 4));
  int* epair         = (int*)(ws + take((size_t)NPAIR * 4));
  size_t part_off    = take((size_t)KSPLIT * NPAIR * DDIM * 2);                  // 32 MiB
  const bool partmode = ws_size >= off;
  size_t wub_off     = take((size_t)NEXP * UDIM * DDIM * 2);                     // 64 MiB
  size_t wdb_off     = take((size_t)NEXP * DDIM * UDIM * 2);                     // 64 MiB
  const bool bf16mode = ws_size >= off;

  hipMemsetAsync(counts, 0, NEXP * CPAD * 4, stream);

  if (bf16mode) {
    unsigned short* part = (unsigned short*)(ws + part_off);
    unsigned short* wub  = (unsigned short*)(ws + wub_off);
    unsigned short* wdb  = (unsigned short*)(ws + wdb_off);
    // router (128 blocks, counting-sort) + fp32->bf16 weight conversion (2048 blocks), fused
    prep_kernel<<<RBLK + CBLK, 256, 0, stream>>>(
        x, w_router, counts, list, wpair, epair, xb, w_up, w_down, wub, wdb);
    stage_up_b16<<<dim3(UDIM / 128, 32, NEXP), 256, 0, stream>>>(
        xb, wub, b_up, counts, list, h);
    stage_down_b16<<<dim3(DDIM / 128, 32 * KSPLIT, NEXP), 256, 0, stream>>>(
        h, wdb, counts, list, part);
    combine_kernel<<<TTOK * DDIM / 8 / 256, 256, 0, stream>>>(part, b_down, wpair, epair, out);
  } else {
    router_kernel<<<TTOK / 4, 256, 0, stream>>>(x, w_router, counts, list, wpair, epair, xb);
    stage_up_k<<<dim3(UDIM / 128, 32, NEXP), 256, 0, stream>>>(xb, w_up, b_up, counts, list, h);
    if (partmode) {
      unsigned short* part = (unsigned short*)(ws + part_off);
      stage_down_k<true><<<dim3(DDIM / 128, 32 * KSPLIT, NEXP), 256, 0, stream>>>(
          h, w_down, b_down, wpair, counts, list, part, out);
      combine_kernel<<<TTOK * DDIM / 8 / 256, 256, 0, stream>>>(part, b_down, wpair, epair, out);
    } else {
      zero_out_k<<<1024, 256, 0, stream>>>((float4v*)out);
      stage_down_k<false><<<dim3(DDIM / 128, 32 * KSPLIT, NEXP), 256, 0, stream>>>(
          h, w_down, b_down, wpair, counts, list, (unsigned short*)nullptr, out);
    }
  }
}